// Round 22
// baseline (304.427 us; speedup 1.0000x reference)
//
#include <hip/hip_runtime.h>
#include <cmath>

#define D 128
#define HID 64

__device__ __forceinline__ float silu_f(float x) { return x / (1.0f + expf(-x)); }

__device__ __forceinline__ float4 fma4(float a, float4 w, float4 c) {
    c.x = fmaf(a, w.x, c.x); c.y = fmaf(a, w.y, c.y);
    c.z = fmaf(a, w.z, c.z); c.w = fmaf(a, w.w, c.w);
    return c;
}
__device__ __forceinline__ float4 silu4(float4 v) {
    v.x = silu_f(v.x); v.y = silu_f(v.y); v.z = silu_f(v.z); v.w = silu_f(v.w);
    return v;
}

#define INIT16(bp) { const float4* _b4 = reinterpret_cast<const float4*>(bp); \
    h0 = _b4[0]; h1 = _b4[1]; h2 = _b4[2]; h3 = _b4[3]; \
    h4 = _b4[4]; h5 = _b4[5]; h6 = _b4[6]; h7 = _b4[7]; \
    h8 = _b4[8]; h9 = _b4[9]; h10 = _b4[10]; h11 = _b4[11]; \
    h12 = _b4[12]; h13 = _b4[13]; h14 = _b4[14]; h15 = _b4[15]; }

#define SILU16() { h0 = silu4(h0); h1 = silu4(h1); h2 = silu4(h2); h3 = silu4(h3); \
    h4 = silu4(h4); h5 = silu4(h5); h6 = silu4(h6); h7 = silu4(h7); \
    h8 = silu4(h8); h9 = silu4(h9); h10 = silu4(h10); h11 = silu4(h11); \
    h12 = silu4(h12); h13 = silu4(h13); h14 = silu4(h14); h15 = silu4(h15); }

// dot with 4 partial sums, k%4 -> s0..s3
__device__ __forceinline__ void fd4(float4 h, float4 w, float& s0, float& s1, float& s2, float& s3) {
    s0 = fmaf(h.x, w.x, s0); s1 = fmaf(h.y, w.y, s1);
    s2 = fmaf(h.z, w.z, s2); s3 = fmaf(h.w, w.w, s3);
}
#define FD16(w4) { fd4(h0, w4[0], s0, s1, s2, s3);  fd4(h1, w4[1], s0, s1, s2, s3);  \
    fd4(h2, w4[2], s0, s1, s2, s3);  fd4(h3, w4[3], s0, s1, s2, s3);  \
    fd4(h4, w4[4], s0, s1, s2, s3);  fd4(h5, w4[5], s0, s1, s2, s3);  \
    fd4(h6, w4[6], s0, s1, s2, s3);  fd4(h7, w4[7], s0, s1, s2, s3);  \
    fd4(h8, w4[8], s0, s1, s2, s3);  fd4(h9, w4[9], s0, s1, s2, s3);  \
    fd4(h10, w4[10], s0, s1, s2, s3); fd4(h11, w4[11], s0, s1, s2, s3); \
    fd4(h12, w4[12], s0, s1, s2, s3); fd4(h13, w4[13], s0, s1, s2, s3); \
    fd4(h14, w4[14], s0, s1, s2, s3); fd4(h15, w4[15], s0, s1, s2, s3); }

// serial silu-dot over 4 units
__device__ __forceinline__ float accdot(float4 h, float4 w, float act) {
    act = fmaf(silu_f(h.x), w.x, act);
    act = fmaf(silu_f(h.y), w.y, act);
    act = fmaf(silu_f(h.z), w.z, act);
    act = fmaf(silu_f(h.w), w.w, act);
    return act;
}

// transpose rw2 (64x64) -> rw2T[j*64+k] = rw2[k*64+j]
__global__ void k_prep(const float* __restrict__ rw2, float* __restrict__ rw2T) {
    int i = blockIdx.x * blockDim.x + threadIdx.x;
    if (i < HID * HID) rw2T[i] = rw2[(i & (HID - 1)) * HID + (i >> 6)];
}

// ---- FUSED node kernel, 16-lane groups x 4 nodes (full-row LDS reads) ----
// phase 1: pw1 in LDS -> mask; block-local partition; phase 2: rw1 in LDS -> uv.
__global__ __launch_bounds__(256) void k_node(
    const float* __restrict__ states, const float* __restrict__ caps,
    const float* __restrict__ pw1, const float* __restrict__ pb1,
    const float* __restrict__ pw2, const float* __restrict__ pb2,
    const float* __restrict__ rw1,
    unsigned* __restrict__ mask, unsigned* __restrict__ mlist,
    unsigned* __restrict__ counters, float* __restrict__ outmask,
    float* __restrict__ uv, int N) {
    __shared__ float wl[16384];                   // 64 KB, reused across phases
    unsigned tid = threadIdx.x;
    unsigned grp = tid >> 4, r = tid & 15u;       // 16 groups; lane r owns units [4r,4r+4)
    unsigned lane = tid & 63u;
    {   // stage pw1: 2064 float4, coalesced
        const float4* s4 = reinterpret_cast<const float4*>(pw1);
        float4* d4 = reinterpret_cast<float4*>(wl);
#pragma unroll
        for (int q = 0; q < 9; ++q) {
            unsigned idx = tid + q * 256u;
            if (idx < 2064u) d4[idx] = s4[idx];
        }
    }
    __syncthreads();
    unsigned nbase = blockIdx.x * 64u + grp * 4u;
    unsigned N1 = (unsigned)(N - 1);
    unsigned n0 = min(nbase + 0u, N1), n1 = min(nbase + 1u, N1);
    unsigned n2 = min(nbase + 2u, N1), n3 = min(nbase + 3u, N1);
    const float4* r0p = reinterpret_cast<const float4*>(states + (size_t)n0 * D);
    const float4* r1p = reinterpret_cast<const float4*>(states + (size_t)n1 * D);
    const float4* r2p = reinterpret_cast<const float4*>(states + (size_t)n2 * D);
    const float4* r3p = reinterpret_cast<const float4*>(states + (size_t)n3 * D);
    unsigned m0, m1, m2, m3;
    {
        float4 a0, a1, a2, a3;
        { float4 b = *reinterpret_cast<const float4*>(pb1 + r * 4);
          a0 = b; a1 = b; a2 = b; a3 = b; }
#pragma unroll 2
        for (int kb = 0; kb < 32; ++kb) {
            float4 x0 = r0p[kb], x1 = r1p[kb], x2 = r2p[kb], x3 = r3p[kb];
            const float* wb = wl + (size_t)kb * 256 + r * 4;
            float4 w;
            w = *reinterpret_cast<const float4*>(wb);
            a0 = fma4(x0.x, w, a0); a1 = fma4(x1.x, w, a1); a2 = fma4(x2.x, w, a2); a3 = fma4(x3.x, w, a3);
            w = *reinterpret_cast<const float4*>(wb + 64);
            a0 = fma4(x0.y, w, a0); a1 = fma4(x1.y, w, a1); a2 = fma4(x2.y, w, a2); a3 = fma4(x3.y, w, a3);
            w = *reinterpret_cast<const float4*>(wb + 128);
            a0 = fma4(x0.z, w, a0); a1 = fma4(x1.z, w, a1); a2 = fma4(x2.z, w, a2); a3 = fma4(x3.z, w, a3);
            w = *reinterpret_cast<const float4*>(wb + 192);
            a0 = fma4(x0.w, w, a0); a1 = fma4(x1.w, w, a1); a2 = fma4(x2.w, w, a2); a3 = fma4(x3.w, w, a3);
        }
        {   // capacity row (input dim 128)
            float c0 = caps[n0], c1 = caps[n1], c2 = caps[n2], c3 = caps[n3];
            float4 wc = *reinterpret_cast<const float4*>(wl + 8192 + r * 4);
            a0 = fma4(c0, wc, a0); a1 = fma4(c1, wc, a1);
            a2 = fma4(c2, wc, a2); a3 = fma4(c3, wc, a3);
        }
        // layer-2 partial over this lane's 4 units, 16-lane butterfly reduce
        float4 w2v = *reinterpret_cast<const float4*>(pw2 + r * 4);
        float p0 = accdot(a0, w2v, 0.f), p1 = accdot(a1, w2v, 0.f);
        float p2 = accdot(a2, w2v, 0.f), p3 = accdot(a3, w2v, 0.f);
#pragma unroll
        for (int mm = 1; mm <= 8; mm <<= 1) {
            p0 += __shfl_xor(p0, mm); p1 += __shfl_xor(p1, mm);
            p2 += __shfl_xor(p2, mm); p3 += __shfl_xor(p3, mm);
        }
        float pb2v = pb2[0];
        m0 = (p0 + pb2v > 0.0f) ? 1u : 0u;
        m1 = (p1 + pb2v > 0.0f) ? 1u : 0u;
        m2 = (p2 + pb2v > 0.0f) ? 1u : 0u;
        m3 = (p3 + pb2v > 0.0f) ? 1u : 0u;
        // write local-mask table (spare LDS beyond pw1's 8256 floats)
        unsigned* lm = reinterpret_cast<unsigned*>(wl + 8320);
        bool v0 = nbase + 0u < (unsigned)N, v1 = nbase + 1u < (unsigned)N;
        bool v2 = nbase + 2u < (unsigned)N, v3 = nbase + 3u < (unsigned)N;
        if (r == 0) {
            lm[grp * 4 + 0] = v0 ? m0 : 0u;
            lm[grp * 4 + 1] = v1 ? m1 : 0u;
            lm[grp * 4 + 2] = v2 ? m2 : 0u;
            lm[grp * 4 + 3] = v3 ? m3 : 0u;
            if (v0) { mask[n0] = m0; outmask[n0] = m0 ? 1.0f : 0.0f; }
            if (v1) { mask[n1] = m1; outmask[n1] = m1 ? 1.0f : 0.0f; }
            if (v2) { mask[n2] = m2; outmask[n2] = m2 ? 1.0f : 0.0f; }
            if (v3) { mask[n3] = m3; outmask[n3] = m3 ? 1.0f : 0.0f; }
        }
#define EMIT(vq, mq, nq) { \
        bool pred = (r == 0) && vq && (mq != 0u); \
        unsigned long long bal = __ballot(pred); \
        unsigned wcnt = (unsigned)__popcll(bal); \
        unsigned pre  = (unsigned)__popcll(bal & ((1ull << lane) - 1ull)); \
        unsigned base = 0; \
        if (lane == 0 && wcnt) base = atomicAdd(&counters[1], wcnt); \
        base = __shfl(base, 0); \
        if (pred) mlist[base + pre] = nq; }
        EMIT(v0, m0, n0) EMIT(v1, m1, n1) EMIT(v2, m2, n2) EMIT(v3, m3, n3)
#undef EMIT
    }
    __syncthreads();                              // lm visible; phase-1 wl reads done
    {   // build partition perm (masked-first) — serial by tid 0
        unsigned* lm = reinterpret_cast<unsigned*>(wl + 8320);
        unsigned* perm = reinterpret_cast<unsigned*>(wl + 8384);
        if (tid == 0) {
            unsigned k = 0;
            for (int i = 0; i < 64; ++i) if (lm[i])  perm[k++] = (unsigned)i;
            for (int i = 0; i < 64; ++i) if (!lm[i]) perm[k++] = (unsigned)i;
        }
    }
    __syncthreads();
    // read my group's phase-2 assignment into registers before wl is overwritten
    unsigned l0, l1, l2, l3, q0m, q1m, q2m, q3m;
    {
        unsigned* lm = reinterpret_cast<unsigned*>(wl + 8320);
        unsigned* perm = reinterpret_cast<unsigned*>(wl + 8384);
        l0 = perm[grp * 4 + 0]; l1 = perm[grp * 4 + 1];
        l2 = perm[grp * 4 + 2]; l3 = perm[grp * 4 + 3];
        q0m = lm[l0]; q1m = lm[l1]; q2m = lm[l2]; q3m = lm[l3];
    }
    __syncthreads();                              // perm/lm reads done
    {   // stage rw1: 4096 float4, coalesced
        const float4* s4 = reinterpret_cast<const float4*>(rw1);
        float4* d4 = reinterpret_cast<float4*>(wl);
#pragma unroll
        for (int q = 0; q < 16; ++q) d4[tid + q * 256u] = s4[tid + q * 256u];
    }
    __syncthreads();
    // phase 2: uv for the permuted nodes
    unsigned pn0 = blockIdx.x * 64u + l0, pn1 = blockIdx.x * 64u + l1;
    unsigned pn2 = blockIdx.x * 64u + l2, pn3 = blockIdx.x * 64u + l3;
    bool pv0 = pn0 < (unsigned)N, pv1 = pn1 < (unsigned)N;
    bool pv2 = pn2 < (unsigned)N, pv3 = pn3 < (unsigned)N;
    const float4* s0p = reinterpret_cast<const float4*>(states + (size_t)min(pn0, N1) * D);
    const float4* s1p = reinterpret_cast<const float4*>(states + (size_t)min(pn1, N1) * D);
    const float4* s2p = reinterpret_cast<const float4*>(states + (size_t)min(pn2, N1) * D);
    const float4* s3p = reinterpret_cast<const float4*>(states + (size_t)min(pn3, N1) * D);
    float4 a0, a1, a2, a3;
    a0.x=a0.y=a0.z=a0.w=0.f; a1=a0; a2=a0; a3=a0;
    if (q0m == q1m && q1m == q2m && q2m == q3m) {
        // uniform group: one row read feeds 4 nodes
        const float* base = wl + (q0m ? 0u : 8192u) + r * 4;
#pragma unroll 2
        for (int kb = 0; kb < 32; ++kb) {
            float4 x0 = s0p[kb], x1 = s1p[kb], x2 = s2p[kb], x3 = s3p[kb];
            const float* wb = base + (size_t)kb * 256;
            float4 w;
            w = *reinterpret_cast<const float4*>(wb);
            a0 = fma4(x0.x, w, a0); a1 = fma4(x1.x, w, a1); a2 = fma4(x2.x, w, a2); a3 = fma4(x3.x, w, a3);
            w = *reinterpret_cast<const float4*>(wb + 64);
            a0 = fma4(x0.y, w, a0); a1 = fma4(x1.y, w, a1); a2 = fma4(x2.y, w, a2); a3 = fma4(x3.y, w, a3);
            w = *reinterpret_cast<const float4*>(wb + 128);
            a0 = fma4(x0.z, w, a0); a1 = fma4(x1.z, w, a1); a2 = fma4(x2.z, w, a2); a3 = fma4(x3.z, w, a3);
            w = *reinterpret_cast<const float4*>(wb + 192);
            a0 = fma4(x0.w, w, a0); a1 = fma4(x1.w, w, a1); a2 = fma4(x2.w, w, a2); a3 = fma4(x3.w, w, a3);
        }
    } else {
        // mixed boundary group: per-node weight base
        const float* b0 = wl + (q0m ? 0u : 8192u) + r * 4;
        const float* b1 = wl + (q1m ? 0u : 8192u) + r * 4;
        const float* b2 = wl + (q2m ? 0u : 8192u) + r * 4;
        const float* b3 = wl + (q3m ? 0u : 8192u) + r * 4;
#pragma unroll 1
        for (int kb = 0; kb < 32; ++kb) {
            float4 x0 = s0p[kb], x1 = s1p[kb], x2 = s2p[kb], x3 = s3p[kb];
            size_t o = (size_t)kb * 256;
#pragma unroll
            for (int u = 0; u < 4; ++u) {
                size_t oo = o + (size_t)u * 64;
                float xv0 = (u == 0) ? x0.x : (u == 1) ? x0.y : (u == 2) ? x0.z : x0.w;
                float xv1 = (u == 0) ? x1.x : (u == 1) ? x1.y : (u == 2) ? x1.z : x1.w;
                float xv2 = (u == 0) ? x2.x : (u == 1) ? x2.y : (u == 2) ? x2.z : x2.w;
                float xv3 = (u == 0) ? x3.x : (u == 1) ? x3.y : (u == 2) ? x3.z : x3.w;
                a0 = fma4(xv0, *reinterpret_cast<const float4*>(b0 + oo), a0);
                a1 = fma4(xv1, *reinterpret_cast<const float4*>(b1 + oo), a1);
                a2 = fma4(xv2, *reinterpret_cast<const float4*>(b2 + oo), a2);
                a3 = fma4(xv3, *reinterpret_cast<const float4*>(b3 + oo), a3);
            }
        }
    }
    if (pv0) *reinterpret_cast<float4*>(uv + (size_t)pn0 * HID + r * 4) = a0;
    if (pv1) *reinterpret_cast<float4*>(uv + (size_t)pn1 * HID + r * 4) = a1;
    if (pv2) *reinterpret_cast<float4*>(uv + (size_t)pn2 * HID + r * 4) = a2;
    if (pv3) *reinterpret_cast<float4*>(uv + (size_t)pn3 * HID + r * 4) = a3;
}

// compact edges with emask = mask[src] && !mask[tgt]; block-aggregated slot alloc
__global__ __launch_bounds__(256) void k_compact(
    const int* __restrict__ ei, const unsigned* __restrict__ mask,
    unsigned* __restrict__ act_eid, unsigned* __restrict__ counters,
    unsigned* __restrict__ hist, int E) {
    __shared__ unsigned wbase[4];
    int e = blockIdx.x * 256 + threadIdx.x;
    unsigned wid = threadIdx.x >> 6, lane = threadIdx.x & 63u;
    bool pred = false; int t = 0;
    if (e < E) {
        int s = ei[e]; t = ei[E + e];
        pred = mask[s] && !mask[t];
    }
    unsigned long long bal = __ballot(pred);
    unsigned wcnt = (unsigned)__popcll(bal);
    unsigned pre  = (unsigned)__popcll(bal & ((1ull << lane) - 1ull));
    if (lane == 0) wbase[wid] = wcnt;
    __syncthreads();
    if (threadIdx.x == 0) {
        unsigned c0 = wbase[0], c1 = wbase[1], c2 = wbase[2], c3 = wbase[3];
        unsigned tot = c0 + c1 + c2 + c3;
        unsigned b = tot ? atomicAdd(&counters[0], tot) : 0u;
        wbase[0] = b; wbase[1] = b + c0; wbase[2] = b + c0 + c1; wbase[3] = b + c0 + c1 + c2;
    }
    __syncthreads();
    if (pred) {
        act_eid[wbase[wid] + pre] = (unsigned)e;
        atomicAdd(&hist[t], 1u);
    }
}

// --- hierarchical exclusive scan of hist[N] -> offs[N+1], cursor[N] ---
__global__ __launch_bounds__(256) void k_scanA(const unsigned* __restrict__ hist,
                                               unsigned* __restrict__ bsum, int N) {
    __shared__ unsigned sm[256];
    unsigned t = threadIdx.x;
    unsigned i = blockIdx.x * 256u + t;
    sm[t] = (i < (unsigned)N) ? hist[i] : 0u;
    __syncthreads();
#pragma unroll
    for (unsigned d = 128; d > 0; d >>= 1) {
        if (t < d) sm[t] += sm[t + d];
        __syncthreads();
    }
    if (t == 0) bsum[blockIdx.x] = sm[0];
}
__global__ __launch_bounds__(256) void k_scanB(const unsigned* __restrict__ bsum,
                                               unsigned* __restrict__ bpre, int nb) {
    __shared__ unsigned sm[256];
    unsigned t = threadIdx.x;
    unsigned v = (t < (unsigned)nb) ? bsum[t] : 0u;
    sm[t] = v;
    __syncthreads();
    for (unsigned d = 1; d < 256; d <<= 1) {
        unsigned x = (t >= d) ? sm[t - d] : 0u;
        __syncthreads();
        sm[t] += x;
        __syncthreads();
    }
    if (t < (unsigned)nb) bpre[t] = sm[t] - v;    // exclusive
}
__global__ __launch_bounds__(256) void k_scanC(const unsigned* __restrict__ hist,
                                               const unsigned* __restrict__ bpre,
                                               unsigned* __restrict__ offs,
                                               unsigned* __restrict__ cursor, int N) {
    __shared__ unsigned sm[256];
    unsigned t = threadIdx.x;
    unsigned i = blockIdx.x * 256u + t;
    unsigned v = (i < (unsigned)N) ? hist[i] : 0u;
    sm[t] = v;
    __syncthreads();
    for (unsigned d = 1; d < 256; d <<= 1) {
        unsigned x = (t >= d) ? sm[t - d] : 0u;
        __syncthreads();
        sm[t] += x;
        __syncthreads();
    }
    unsigned exc = sm[t] - v + bpre[blockIdx.x];
    if (i < (unsigned)N) { offs[i] = exc; cursor[i] = exc; }
    if (i == (unsigned)N - 1) offs[N] = exc + v;
}

// ---- edge MLP + exp + bucket (no max-shift: softmax is shift-invariant; raw is O(1)) ----
__global__ __launch_bounds__(256) void k_edge_mlp(
    const float* __restrict__ uv, const int* __restrict__ ei,
    const float* __restrict__ rb1, const float* __restrict__ rw2T,
    const float* __restrict__ rb2, const float* __restrict__ rw3,
    const float* __restrict__ rb3,
    const unsigned* __restrict__ act_eid, const unsigned* __restrict__ counters,
    float* __restrict__ denom, unsigned* __restrict__ cursor,
    float* __restrict__ wbuf, unsigned* __restrict__ sbuf, int E) {
    unsigned cnt = counters[0];
    if (blockIdx.x * 256u >= cnt) return;         // whole block inactive (uniform)
    unsigned tid = threadIdx.x;
    unsigned grp = blockIdx.x * 256u + tid;
    bool active = grp < cnt;
    unsigned gq = active ? grp : (cnt - 1);
    int e = (int)act_eid[gq];
    int s = ei[e], tg = ei[E + e];
    const float4* ur = reinterpret_cast<const float4*>(uv + (size_t)s * HID);
    const float4* vr = reinterpret_cast<const float4*>(uv + (size_t)tg * HID);
    float4 h0, h1, h2, h3, h4, h5, h6, h7, h8, h9, h10, h11, h12, h13, h14, h15;
    INIT16(rb1);
#define ADDUV(hh, i) { float4 _u = ur[i]; float4 _v = vr[i]; \
    hh.x = hh.x + _u.x + _v.x; hh.y = hh.y + _u.y + _v.y; \
    hh.z = hh.z + _u.z + _v.z; hh.w = hh.w + _u.w + _v.w; }
    ADDUV(h0, 0)  ADDUV(h1, 1)  ADDUV(h2, 2)  ADDUV(h3, 3)
    ADDUV(h4, 4)  ADDUV(h5, 5)  ADDUV(h6, 6)  ADDUV(h7, 7)
    ADDUV(h8, 8)  ADDUV(h9, 9)  ADDUV(h10, 10) ADDUV(h11, 11)
    ADDUV(h12, 12) ADDUV(h13, 13) ADDUV(h14, 14) ADDUV(h15, 15)
#undef ADDUV
    SILU16();
    float raw = rb3[0];
#pragma unroll 1
    for (int j = 0; j < HID; ++j) {
        const float4* w4 = reinterpret_cast<const float4*>(rw2T + (size_t)j * HID);
        float s0 = rb2[j], s1 = 0.f, s2 = 0.f, s3 = 0.f;
        FD16(w4);
        float h2v = silu_f((s0 + s1) + (s2 + s3));
        raw = fmaf(h2v, rw3[j], raw);
    }
    if (active) {
        float ev = expf(raw);
        atomicAdd(&denom[s], ev);
        unsigned pos = atomicAdd(&cursor[tg], 1u);
        wbuf[pos] = ev;
        sbuf[pos] = (unsigned)s;
    }
}

// wave per node: out[n] = states[n] + sum_{incoming active} (ev/denom[s]) * states[src]
__global__ __launch_bounds__(256) void k_gather(
    const float* __restrict__ states, const float* __restrict__ wbuf,
    const unsigned* __restrict__ sbuf, const unsigned* __restrict__ offs,
    const float* __restrict__ denom, const unsigned* __restrict__ mask,
    float* __restrict__ out, int N) {
    unsigned n = blockIdx.x * 4u + (threadIdx.x >> 6);
    unsigned lane = threadIdx.x & 63u;
    if (n >= (unsigned)N) return;
    if (mask[n]) return;                          // overwritten by k_jump
    unsigned start = offs[n], end = offs[n + 1];
    float2 acc = reinterpret_cast<const float2*>(states + (size_t)n * D)[lane];
    for (unsigned i = start; i < end; ++i) {
        unsigned s = sbuf[i];
        float w = wbuf[i] / denom[s];
        float2 sv = reinterpret_cast<const float2*>(states + (size_t)s * D)[lane];
        acc.x = fmaf(w, sv.x, acc.x);
        acc.y = fmaf(w, sv.y, acc.y);
    }
    reinterpret_cast<float2*>(out + (size_t)n * D)[lane] = acc;
}

// failed nodes: out = tanh(states @ tw + tb) * 0.05
__global__ __launch_bounds__(256) void k_jump(
    const float* __restrict__ states,
    const float* __restrict__ tw, const float* __restrict__ tb,
    const unsigned* __restrict__ mlist, const unsigned* __restrict__ counters,
    float* __restrict__ out) {
    __shared__ float xs[8][D];
    unsigned cnt = counters[1];
    unsigned base = blockIdx.x * 8u;
    if (base >= cnt || cnt == 0) return;          // uniform
    unsigned tid = threadIdx.x;
    unsigned d = tid & 127u, r = tid >> 7;        // r in {0,1}
    {   // stage 8 rows (clamped): 32 threads per row, float4 each
        unsigned j = tid >> 5;
        unsigned c = (tid & 31u) * 4u;
        unsigned slot = base + j; if (slot >= cnt) slot = cnt - 1;
        int nn = (int)mlist[slot];
        *reinterpret_cast<float4*>(&xs[j][c]) =
            *reinterpret_cast<const float4*>(&states[(size_t)nn * D + c]);
    }
    __syncthreads();
    float tbd = tb[d];
    float a0 = tbd, a1 = tbd, a2 = tbd, a3 = tbd;
    const float* x0 = &xs[r * 4 + 0][0];
    const float* x1 = &xs[r * 4 + 1][0];
    const float* x2 = &xs[r * 4 + 2][0];
    const float* x3 = &xs[r * 4 + 3][0];
#pragma unroll 1
    for (int k = 0; k < D; ++k) {
        float w = tw[(size_t)k * D + d];
        a0 = fmaf(x0[k], w, a0);
        a1 = fmaf(x1[k], w, a1);
        a2 = fmaf(x2[k], w, a2);
        a3 = fmaf(x3[k], w, a3);
    }
    float res[4] = {a0, a1, a2, a3};
#pragma unroll
    for (int j2 = 0; j2 < 4; ++j2) {
        unsigned slot = base + r * 4 + j2;
        if (slot < cnt) {
            int nn = (int)mlist[slot];
            out[(size_t)nn * D + d] = tanhf(res[j2]) * 0.05f;
        }
    }
}

extern "C" void kernel_launch(void* const* d_in, const int* in_sizes, int n_in,
                              void* d_out, int out_size, void* d_ws, size_t ws_size,
                              hipStream_t stream) {
    const float* states = (const float*)d_in[0];
    const float* caps   = (const float*)d_in[1];
    const int*   ei     = (const int*)d_in[2];
    const float* rw1 = (const float*)d_in[3];  const float* rb1 = (const float*)d_in[4];
    const float* rw2 = (const float*)d_in[5];  const float* rb2 = (const float*)d_in[6];
    const float* rw3 = (const float*)d_in[7];  const float* rb3 = (const float*)d_in[8];
    const float* pw1 = (const float*)d_in[9];  const float* pb1 = (const float*)d_in[10];
    const float* pw2 = (const float*)d_in[11]; const float* pb2 = (const float*)d_in[12];
    const float* tw  = (const float*)d_in[13]; const float* tb  = (const float*)d_in[14];
    const int N = in_sizes[1];
    const int E = in_sizes[2] / 2;
    float* out = (float*)d_out;
    const int nb = (N + 255) / 256;

    // uv lives in d_out[0 : N*HID) — dead scratch until k_gather/k_jump write out.
    float* uv = out;

    // ws layout (u32 units):
    // [0..3] counters | denom N | hist N | mask N | mlist N |
    // offs N+1 | cursor N | bsum 256 | bpre 256 | act_eid E | wbuf E | sbuf E | rw2T 4096
    unsigned* ws       = (unsigned*)d_ws;
    unsigned* counters = ws;
    float*    denom    = (float*)(ws + 4);
    unsigned* hist     = ws + 4 + 1 * (size_t)N;
    unsigned* mask     = ws + 4 + 2 * (size_t)N;
    unsigned* mlist    = ws + 4 + 3 * (size_t)N;
    unsigned* offs     = ws + 4 + 4 * (size_t)N;
    unsigned* cursor   = ws + 4 + 5 * (size_t)N + 1;
    unsigned* bsum     = ws + 4 + 6 * (size_t)N + 1;
    unsigned* bpre     = bsum + 256;
    unsigned* act_eid  = bpre + 256;
    float*    wbuf     = (float*)(act_eid + (size_t)E);
    unsigned* sbuf     = act_eid + 2 * (size_t)E;
    float*    rw2T     = (float*)(act_eid + 3 * (size_t)E);

    // zero counters + denom + hist (contiguous prefix)
    (void)hipMemsetAsync(d_ws, 0, (size_t)(4 + 2 * (size_t)N) * 4, stream);

    k_prep<<<(HID * HID + 255) / 256, 256, 0, stream>>>(rw2, rw2T);
    k_node<<<(N + 63) / 64, 256, 0, stream>>>(states, caps, pw1, pb1, pw2, pb2, rw1,
                                              mask, mlist, counters, out + (size_t)N * D, uv, N);
    k_compact<<<(E + 255) / 256, 256, 0, stream>>>(ei, mask, act_eid, counters, hist, E);
    k_scanA<<<nb, 256, 0, stream>>>(hist, bsum, N);
    k_scanB<<<1, 256, 0, stream>>>(bsum, bpre, nb);
    k_scanC<<<nb, 256, 0, stream>>>(hist, bpre, offs, cursor, N);
    k_edge_mlp<<<(E + 255) / 256, 256, 0, stream>>>(uv, ei, rb1, rw2T, rb2, rw3, rb3,
                                                    act_eid, counters, denom, cursor,
                                                    wbuf, sbuf, E);
    k_gather<<<(N + 3) / 4, 256, 0, stream>>>(states, wbuf, sbuf, offs, denom, mask, out, N);
    k_jump<<<(N + 7) / 8, 256, 0, stream>>>(states, tw, tb, mlist, counters, out);
}

// Round 23
// 256.148 us; speedup vs baseline: 1.1885x; 1.1885x over previous
//
#include <hip/hip_runtime.h>
#include <cmath>

#define D 128
#define HID 64

__device__ __forceinline__ float silu_f(float x) { return x / (1.0f + expf(-x)); }

__device__ __forceinline__ float4 fma4(float a, float4 w, float4 c) {
    c.x = fmaf(a, w.x, c.x); c.y = fmaf(a, w.y, c.y);
    c.z = fmaf(a, w.z, c.z); c.w = fmaf(a, w.w, c.w);
    return c;
}
__device__ __forceinline__ float4 silu4(float4 v) {
    v.x = silu_f(v.x); v.y = silu_f(v.y); v.z = silu_f(v.z); v.w = silu_f(v.w);
    return v;
}

#define INIT16(bp) { const float4* _b4 = reinterpret_cast<const float4*>(bp); \
    h0 = _b4[0]; h1 = _b4[1]; h2 = _b4[2]; h3 = _b4[3]; \
    h4 = _b4[4]; h5 = _b4[5]; h6 = _b4[6]; h7 = _b4[7]; \
    h8 = _b4[8]; h9 = _b4[9]; h10 = _b4[10]; h11 = _b4[11]; \
    h12 = _b4[12]; h13 = _b4[13]; h14 = _b4[14]; h15 = _b4[15]; }

#define SILU16() { h0 = silu4(h0); h1 = silu4(h1); h2 = silu4(h2); h3 = silu4(h3); \
    h4 = silu4(h4); h5 = silu4(h5); h6 = silu4(h6); h7 = silu4(h7); \
    h8 = silu4(h8); h9 = silu4(h9); h10 = silu4(h10); h11 = silu4(h11); \
    h12 = silu4(h12); h13 = silu4(h13); h14 = silu4(h14); h15 = silu4(h15); }

// dot with 4 partial sums, k%4 -> s0..s3
__device__ __forceinline__ void fd4(float4 h, float4 w, float& s0, float& s1, float& s2, float& s3) {
    s0 = fmaf(h.x, w.x, s0); s1 = fmaf(h.y, w.y, s1);
    s2 = fmaf(h.z, w.z, s2); s3 = fmaf(h.w, w.w, s3);
}
#define FD16(w4) { fd4(h0, w4[0], s0, s1, s2, s3);  fd4(h1, w4[1], s0, s1, s2, s3);  \
    fd4(h2, w4[2], s0, s1, s2, s3);  fd4(h3, w4[3], s0, s1, s2, s3);  \
    fd4(h4, w4[4], s0, s1, s2, s3);  fd4(h5, w4[5], s0, s1, s2, s3);  \
    fd4(h6, w4[6], s0, s1, s2, s3);  fd4(h7, w4[7], s0, s1, s2, s3);  \
    fd4(h8, w4[8], s0, s1, s2, s3);  fd4(h9, w4[9], s0, s1, s2, s3);  \
    fd4(h10, w4[10], s0, s1, s2, s3); fd4(h11, w4[11], s0, s1, s2, s3); \
    fd4(h12, w4[12], s0, s1, s2, s3); fd4(h13, w4[13], s0, s1, s2, s3); \
    fd4(h14, w4[14], s0, s1, s2, s3); fd4(h15, w4[15], s0, s1, s2, s3); }

// serial silu-dot over 4 units
__device__ __forceinline__ float accdot(float4 h, float4 w, float act) {
    act = fmaf(silu_f(h.x), w.x, act);
    act = fmaf(silu_f(h.y), w.y, act);
    act = fmaf(silu_f(h.z), w.z, act);
    act = fmaf(silu_f(h.w), w.w, act);
    return act;
}

// transpose rw2 (64x64) -> rw2T[j*64+k] = rw2[k*64+j]
__global__ void k_prep(const float* __restrict__ rw2, float* __restrict__ rw2T) {
    int i = blockIdx.x * blockDim.x + threadIdx.x;
    if (i < HID * HID) rw2T[i] = rw2[(i & (HID - 1)) * HID + (i >> 6)];
}

// ---- FUSED: protection net + per-node layer-1 uv; 4 lanes/node, 64 nodes/block ----
// phase 1: pw1 in LDS -> mask (kept in-register); phase 2: rw1 in LDS -> uv.
__global__ __launch_bounds__(256) void k_node(
    const float* __restrict__ states, const float* __restrict__ caps,
    const float* __restrict__ pw1, const float* __restrict__ pb1,
    const float* __restrict__ pw2, const float* __restrict__ pb2,
    const float* __restrict__ rw1,
    unsigned* __restrict__ mask, unsigned* __restrict__ mlist,
    unsigned* __restrict__ counters, float* __restrict__ outmask,
    float* __restrict__ uv, int N) {
    __shared__ float wl[16384];                   // 64 KB, reused across phases
    unsigned tid = threadIdx.x;
    {   // stage pw1: 2064 float4, coalesced
        const float4* s4 = reinterpret_cast<const float4*>(pw1);
        float4* d4 = reinterpret_cast<float4*>(wl);
#pragma unroll
        for (int q = 0; q < 9; ++q) {
            unsigned idx = tid + q * 256u;
            if (idx < 2064u) d4[idx] = s4[idx];
        }
    }
    __syncthreads();
    unsigned nl = tid >> 2, g = tid & 3u;         // lane g owns hidden units [g*16, g*16+16)
    unsigned n = blockIdx.x * 64u + nl;
    bool active = n < (unsigned)N;
    unsigned nq = active ? n : (unsigned)(N - 1);
    const float4* row = reinterpret_cast<const float4*>(states + (size_t)nq * D);
    unsigned m;
    {
        float4 a0, a1, a2, a3;
        { const float4* b4 = reinterpret_cast<const float4*>(pb1 + g * 16);
          a0 = b4[0]; a1 = b4[1]; a2 = b4[2]; a3 = b4[3]; }
        const float* wg = wl + g * 16;
#pragma unroll 4
        for (int kb = 0; kb < 32; ++kb) {
            float4 x = row[kb];
            const float* w = wg + (size_t)kb * 4 * HID;
            const float4* w0 = reinterpret_cast<const float4*>(w);
            const float4* w1 = reinterpret_cast<const float4*>(w + HID);
            const float4* w2q = reinterpret_cast<const float4*>(w + 2 * HID);
            const float4* w3q = reinterpret_cast<const float4*>(w + 3 * HID);
            a0 = fma4(x.x, w0[0], a0); a1 = fma4(x.x, w0[1], a1); a2 = fma4(x.x, w0[2], a2); a3 = fma4(x.x, w0[3], a3);
            a0 = fma4(x.y, w1[0], a0); a1 = fma4(x.y, w1[1], a1); a2 = fma4(x.y, w1[2], a2); a3 = fma4(x.y, w1[3], a3);
            a0 = fma4(x.z, w2q[0], a0); a1 = fma4(x.z, w2q[1], a1); a2 = fma4(x.z, w2q[2], a2); a3 = fma4(x.z, w2q[3], a3);
            a0 = fma4(x.w, w3q[0], a0); a1 = fma4(x.w, w3q[1], a1); a2 = fma4(x.w, w3q[2], a2); a3 = fma4(x.w, w3q[3], a3);
        }
        {   // capacity row (input dim 128)
            float xv = caps[nq];
            const float4* wc = reinterpret_cast<const float4*>(wg + (size_t)128 * HID);
            a0 = fma4(xv, wc[0], a0); a1 = fma4(xv, wc[1], a1);
            a2 = fma4(xv, wc[2], a2); a3 = fma4(xv, wc[3], a3);
        }
        // layer-2 partial over this lane's 16 units, then 4-lane butterfly reduce
        const float4* w2 = reinterpret_cast<const float4*>(pw2 + g * 16);
        float p = 0.0f;
        p = accdot(a0, w2[0], p); p = accdot(a1, w2[1], p);
        p = accdot(a2, w2[2], p); p = accdot(a3, w2[3], p);
        p += __shfl_xor(p, 1);
        p += __shfl_xor(p, 2);                    // all 4 lanes: full (identical) sum
        float act = p + pb2[0];
        m = (act > 0.0f) ? 1u : 0u;
        bool pred = false;
        if (active && g == 0) {
            mask[n] = m;
            outmask[n] = m ? 1.0f : 0.0f;
            pred = (m != 0u);
        }
        unsigned lane = tid & 63u;
        unsigned long long bal = __ballot(pred);
        unsigned wcnt = (unsigned)__popcll(bal);
        unsigned pre  = (unsigned)__popcll(bal & ((1ull << lane) - 1ull));
        unsigned base = 0;
        if (lane == 0 && wcnt) base = atomicAdd(&counters[1], wcnt);
        base = __shfl(base, 0);
        if (pred) mlist[base + pre] = n;
    }
    __syncthreads();                              // all reads of pw1 done
    {   // stage rw1: 4096 float4, coalesced
        const float4* s4 = reinterpret_cast<const float4*>(rw1);
        float4* d4 = reinterpret_cast<float4*>(wl);
#pragma unroll
        for (int q = 0; q < 16; ++q) d4[tid + q * 256u] = s4[tid + q * 256u];
    }
    __syncthreads();
    if (!active) return;
    // uv[n] = (m ? W1a : W1b) @ states[n]
    const float* wg = wl + (m ? 0u : 8192u) + g * 16;
    float4 a0, a1, a2, a3;
    a0.x=a0.y=a0.z=a0.w=0.f; a1=a0; a2=a0; a3=a0;
#pragma unroll 4
    for (int kb = 0; kb < 32; ++kb) {
        float4 x = row[kb];
        const float* w = wg + (size_t)kb * 4 * HID;
        const float4* w0 = reinterpret_cast<const float4*>(w);
        const float4* w1 = reinterpret_cast<const float4*>(w + HID);
        const float4* w2q = reinterpret_cast<const float4*>(w + 2 * HID);
        const float4* w3q = reinterpret_cast<const float4*>(w + 3 * HID);
        a0 = fma4(x.x, w0[0], a0); a1 = fma4(x.x, w0[1], a1); a2 = fma4(x.x, w0[2], a2); a3 = fma4(x.x, w0[3], a3);
        a0 = fma4(x.y, w1[0], a0); a1 = fma4(x.y, w1[1], a1); a2 = fma4(x.y, w1[2], a2); a3 = fma4(x.y, w1[3], a3);
        a0 = fma4(x.z, w2q[0], a0); a1 = fma4(x.z, w2q[1], a1); a2 = fma4(x.z, w2q[2], a2); a3 = fma4(x.z, w2q[3], a3);
        a0 = fma4(x.w, w3q[0], a0); a1 = fma4(x.w, w3q[1], a1); a2 = fma4(x.w, w3q[2], a2); a3 = fma4(x.w, w3q[3], a3);
    }
    float4* o = reinterpret_cast<float4*>(uv + (size_t)n * HID + g * 16);
    o[0] = a0; o[1] = a1; o[2] = a2; o[3] = a3;
}

// compact edges with emask = mask[src] && !mask[tgt]; block-aggregated slot alloc
__global__ __launch_bounds__(256) void k_compact(
    const int* __restrict__ ei, const unsigned* __restrict__ mask,
    unsigned* __restrict__ act_eid, unsigned* __restrict__ counters,
    unsigned* __restrict__ hist, int E) {
    __shared__ unsigned wbase[4];
    int e = blockIdx.x * 256 + threadIdx.x;
    unsigned wid = threadIdx.x >> 6, lane = threadIdx.x & 63u;
    bool pred = false; int t = 0;
    if (e < E) {
        int s = ei[e]; t = ei[E + e];
        pred = mask[s] && !mask[t];
    }
    unsigned long long bal = __ballot(pred);
    unsigned wcnt = (unsigned)__popcll(bal);
    unsigned pre  = (unsigned)__popcll(bal & ((1ull << lane) - 1ull));
    if (lane == 0) wbase[wid] = wcnt;
    __syncthreads();
    if (threadIdx.x == 0) {
        unsigned c0 = wbase[0], c1 = wbase[1], c2 = wbase[2], c3 = wbase[3];
        unsigned tot = c0 + c1 + c2 + c3;
        unsigned b = tot ? atomicAdd(&counters[0], tot) : 0u;
        wbase[0] = b; wbase[1] = b + c0; wbase[2] = b + c0 + c1; wbase[3] = b + c0 + c1 + c2;
    }
    __syncthreads();
    if (pred) {
        act_eid[wbase[wid] + pre] = (unsigned)e;
        atomicAdd(&hist[t], 1u);
    }
}

// --- hierarchical exclusive scan of hist[N] -> offs[N+1], cursor[N] ---
__global__ __launch_bounds__(256) void k_scanA(const unsigned* __restrict__ hist,
                                               unsigned* __restrict__ bsum, int N) {
    __shared__ unsigned sm[256];
    unsigned t = threadIdx.x;
    unsigned i = blockIdx.x * 256u + t;
    sm[t] = (i < (unsigned)N) ? hist[i] : 0u;
    __syncthreads();
#pragma unroll
    for (unsigned d = 128; d > 0; d >>= 1) {
        if (t < d) sm[t] += sm[t + d];
        __syncthreads();
    }
    if (t == 0) bsum[blockIdx.x] = sm[0];
}
__global__ __launch_bounds__(256) void k_scanB(const unsigned* __restrict__ bsum,
                                               unsigned* __restrict__ bpre, int nb) {
    __shared__ unsigned sm[256];
    unsigned t = threadIdx.x;
    unsigned v = (t < (unsigned)nb) ? bsum[t] : 0u;
    sm[t] = v;
    __syncthreads();
    for (unsigned d = 1; d < 256; d <<= 1) {
        unsigned x = (t >= d) ? sm[t - d] : 0u;
        __syncthreads();
        sm[t] += x;
        __syncthreads();
    }
    if (t < (unsigned)nb) bpre[t] = sm[t] - v;    // exclusive
}
__global__ __launch_bounds__(256) void k_scanC(const unsigned* __restrict__ hist,
                                               const unsigned* __restrict__ bpre,
                                               unsigned* __restrict__ offs,
                                               unsigned* __restrict__ cursor, int N) {
    __shared__ unsigned sm[256];
    unsigned t = threadIdx.x;
    unsigned i = blockIdx.x * 256u + t;
    unsigned v = (i < (unsigned)N) ? hist[i] : 0u;
    sm[t] = v;
    __syncthreads();
    for (unsigned d = 1; d < 256; d <<= 1) {
        unsigned x = (t >= d) ? sm[t - d] : 0u;
        __syncthreads();
        sm[t] += x;
        __syncthreads();
    }
    unsigned exc = sm[t] - v + bpre[blockIdx.x];
    if (i < (unsigned)N) { offs[i] = exc; cursor[i] = exc; }
    if (i == (unsigned)N - 1) offs[N] = exc + v;
}

// ---- edge MLP + exp + bucket (no max-shift: softmax is shift-invariant; raw is O(1)) ----
__global__ __launch_bounds__(256) void k_edge_mlp(
    const float* __restrict__ uv, const int* __restrict__ ei,
    const float* __restrict__ rb1, const float* __restrict__ rw2T,
    const float* __restrict__ rb2, const float* __restrict__ rw3,
    const float* __restrict__ rb3,
    const unsigned* __restrict__ act_eid, const unsigned* __restrict__ counters,
    float* __restrict__ denom, unsigned* __restrict__ cursor,
    float* __restrict__ wbuf, unsigned* __restrict__ sbuf, int E) {
    unsigned cnt = counters[0];
    if (blockIdx.x * 256u >= cnt) return;         // whole block inactive (uniform)
    unsigned tid = threadIdx.x;
    unsigned grp = blockIdx.x * 256u + tid;
    bool active = grp < cnt;
    unsigned gq = active ? grp : (cnt - 1);
    int e = (int)act_eid[gq];
    int s = ei[e], tg = ei[E + e];
    const float4* ur = reinterpret_cast<const float4*>(uv + (size_t)s * HID);
    const float4* vr = reinterpret_cast<const float4*>(uv + (size_t)tg * HID);
    float4 h0, h1, h2, h3, h4, h5, h6, h7, h8, h9, h10, h11, h12, h13, h14, h15;
    INIT16(rb1);
#define ADDUV(hh, i) { float4 _u = ur[i]; float4 _v = vr[i]; \
    hh.x = hh.x + _u.x + _v.x; hh.y = hh.y + _u.y + _v.y; \
    hh.z = hh.z + _u.z + _v.z; hh.w = hh.w + _u.w + _v.w; }
    ADDUV(h0, 0)  ADDUV(h1, 1)  ADDUV(h2, 2)  ADDUV(h3, 3)
    ADDUV(h4, 4)  ADDUV(h5, 5)  ADDUV(h6, 6)  ADDUV(h7, 7)
    ADDUV(h8, 8)  ADDUV(h9, 9)  ADDUV(h10, 10) ADDUV(h11, 11)
    ADDUV(h12, 12) ADDUV(h13, 13) ADDUV(h14, 14) ADDUV(h15, 15)
#undef ADDUV
    SILU16();
    float raw = rb3[0];
#pragma unroll 1
    for (int j = 0; j < HID; ++j) {
        const float4* w4 = reinterpret_cast<const float4*>(rw2T + (size_t)j * HID);
        float s0 = rb2[j], s1 = 0.f, s2 = 0.f, s3 = 0.f;
        FD16(w4);
        float h2v = silu_f((s0 + s1) + (s2 + s3));
        raw = fmaf(h2v, rw3[j], raw);
    }
    if (active) {
        float ev = expf(raw);
        atomicAdd(&denom[s], ev);
        unsigned pos = atomicAdd(&cursor[tg], 1u);
        wbuf[pos] = ev;
        sbuf[pos] = (unsigned)s;
    }
}

// wave per node: out[n] = states[n] + sum_{incoming active} (ev/denom[s]) * states[src]
__global__ __launch_bounds__(256) void k_gather(
    const float* __restrict__ states, const float* __restrict__ wbuf,
    const unsigned* __restrict__ sbuf, const unsigned* __restrict__ offs,
    const float* __restrict__ denom, const unsigned* __restrict__ mask,
    float* __restrict__ out, int N) {
    unsigned n = blockIdx.x * 4u + (threadIdx.x >> 6);
    unsigned lane = threadIdx.x & 63u;
    if (n >= (unsigned)N) return;
    if (mask[n]) return;                          // overwritten by k_jump
    unsigned start = offs[n], end = offs[n + 1];
    float2 acc = reinterpret_cast<const float2*>(states + (size_t)n * D)[lane];
    for (unsigned i = start; i < end; ++i) {
        unsigned s = sbuf[i];
        float w = wbuf[i] / denom[s];
        float2 sv = reinterpret_cast<const float2*>(states + (size_t)s * D)[lane];
        acc.x = fmaf(w, sv.x, acc.x);
        acc.y = fmaf(w, sv.y, acc.y);
    }
    reinterpret_cast<float2*>(out + (size_t)n * D)[lane] = acc;
}

// failed nodes: out = tanh(states @ tw + tb) * 0.05
__global__ __launch_bounds__(256) void k_jump(
    const float* __restrict__ states,
    const float* __restrict__ tw, const float* __restrict__ tb,
    const unsigned* __restrict__ mlist, const unsigned* __restrict__ counters,
    float* __restrict__ out) {
    __shared__ float xs[8][D];
    unsigned cnt = counters[1];
    unsigned base = blockIdx.x * 8u;
    if (base >= cnt || cnt == 0) return;          // uniform
    unsigned tid = threadIdx.x;
    unsigned d = tid & 127u, r = tid >> 7;        // r in {0,1}
    {   // stage 8 rows (clamped): 32 threads per row, float4 each
        unsigned j = tid >> 5;
        unsigned c = (tid & 31u) * 4u;
        unsigned slot = base + j; if (slot >= cnt) slot = cnt - 1;
        int nn = (int)mlist[slot];
        *reinterpret_cast<float4*>(&xs[j][c]) =
            *reinterpret_cast<const float4*>(&states[(size_t)nn * D + c]);
    }
    __syncthreads();
    float tbd = tb[d];
    float a0 = tbd, a1 = tbd, a2 = tbd, a3 = tbd;
    const float* x0 = &xs[r * 4 + 0][0];
    const float* x1 = &xs[r * 4 + 1][0];
    const float* x2 = &xs[r * 4 + 2][0];
    const float* x3 = &xs[r * 4 + 3][0];
#pragma unroll 1
    for (int k = 0; k < D; ++k) {
        float w = tw[(size_t)k * D + d];
        a0 = fmaf(x0[k], w, a0);
        a1 = fmaf(x1[k], w, a1);
        a2 = fmaf(x2[k], w, a2);
        a3 = fmaf(x3[k], w, a3);
    }
    float res[4] = {a0, a1, a2, a3};
#pragma unroll
    for (int j2 = 0; j2 < 4; ++j2) {
        unsigned slot = base + r * 4 + j2;
        if (slot < cnt) {
            int nn = (int)mlist[slot];
            out[(size_t)nn * D + d] = tanhf(res[j2]) * 0.05f;
        }
    }
}

extern "C" void kernel_launch(void* const* d_in, const int* in_sizes, int n_in,
                              void* d_out, int out_size, void* d_ws, size_t ws_size,
                              hipStream_t stream) {
    const float* states = (const float*)d_in[0];
    const float* caps   = (const float*)d_in[1];
    const int*   ei     = (const int*)d_in[2];
    const float* rw1 = (const float*)d_in[3];  const float* rb1 = (const float*)d_in[4];
    const float* rw2 = (const float*)d_in[5];  const float* rb2 = (const float*)d_in[6];
    const float* rw3 = (const float*)d_in[7];  const float* rb3 = (const float*)d_in[8];
    const float* pw1 = (const float*)d_in[9];  const float* pb1 = (const float*)d_in[10];
    const float* pw2 = (const float*)d_in[11]; const float* pb2 = (const float*)d_in[12];
    const float* tw  = (const float*)d_in[13]; const float* tb  = (const float*)d_in[14];
    const int N = in_sizes[1];
    const int E = in_sizes[2] / 2;
    float* out = (float*)d_out;
    const int nb = (N + 255) / 256;

    // uv lives in d_out[0 : N*HID) — dead scratch until k_gather/k_jump write out.
    float* uv = out;

    // ws layout (u32 units):
    // [0..3] counters | denom N | hist N | mask N | mlist N |
    // offs N+1 | cursor N | bsum 256 | bpre 256 | act_eid E | wbuf E | sbuf E | rw2T 4096
    unsigned* ws       = (unsigned*)d_ws;
    unsigned* counters = ws;
    float*    denom    = (float*)(ws + 4);
    unsigned* hist     = ws + 4 + 1 * (size_t)N;
    unsigned* mask     = ws + 4 + 2 * (size_t)N;
    unsigned* mlist    = ws + 4 + 3 * (size_t)N;
    unsigned* offs     = ws + 4 + 4 * (size_t)N;
    unsigned* cursor   = ws + 4 + 5 * (size_t)N + 1;
    unsigned* bsum     = ws + 4 + 6 * (size_t)N + 1;
    unsigned* bpre     = bsum + 256;
    unsigned* act_eid  = bpre + 256;
    float*    wbuf     = (float*)(act_eid + (size_t)E);
    unsigned* sbuf     = act_eid + 2 * (size_t)E;
    float*    rw2T     = (float*)(act_eid + 3 * (size_t)E);

    // zero counters + denom + hist (contiguous prefix)
    (void)hipMemsetAsync(d_ws, 0, (size_t)(4 + 2 * (size_t)N) * 4, stream);

    k_prep<<<(HID * HID + 255) / 256, 256, 0, stream>>>(rw2, rw2T);
    k_node<<<(N + 63) / 64, 256, 0, stream>>>(states, caps, pw1, pb1, pw2, pb2, rw1,
                                              mask, mlist, counters, out + (size_t)N * D, uv, N);
    k_compact<<<(E + 255) / 256, 256, 0, stream>>>(ei, mask, act_eid, counters, hist, E);
    k_scanA<<<nb, 256, 0, stream>>>(hist, bsum, N);
    k_scanB<<<1, 256, 0, stream>>>(bsum, bpre, nb);
    k_scanC<<<nb, 256, 0, stream>>>(hist, bpre, offs, cursor, N);
    k_edge_mlp<<<(E + 255) / 256, 256, 0, stream>>>(uv, ei, rb1, rw2T, rb2, rw3, rb3,
                                                    act_eid, counters, denom, cursor,
                                                    wbuf, sbuf, E);
    k_gather<<<(N + 3) / 4, 256, 0, stream>>>(states, wbuf, sbuf, offs, denom, mask, out, N);
    k_jump<<<(N + 7) / 8, 256, 0, stream>>>(states, tw, tb, mlist, counters, out);
}